// Round 19
// baseline (465.588 us; speedup 1.0000x reference)
//
#include <hip/hip_runtime.h>

// Problem constants (fixed by the reference: N = 512*512, E = N*8, grid 512)
#define NN 262144
#define NE 2097152
constexpr int GS = 512;
constexpr int P  = GS * GS;   // == NN
constexpr int BSTRIDE = 12288; // per-bucket ssrc slot stride (4-aligned segs)
constexpr int PADP = 1024;     // pixel-row zero pad for conv1 MFMA gathers
constexpr int PADP2 = 1024;    // pixel-row zero pad for conv2 MFMA gathers

typedef __attribute__((ext_vector_type(16))) float f32x16;
typedef __attribute__((ext_vector_type(8)))  float f32x8;
typedef __attribute__((ext_vector_type(4)))  float f32x4;
typedef __attribute__((ext_vector_type(2)))  float f32x2;
typedef __attribute__((ext_vector_type(8)))  short s16x8;   // bf16x8 MFMA frag

__device__ __forceinline__ unsigned short f2bf(float f) {   // RNE fp32->bf16
  unsigned u = __float_as_uint(f);
  return (unsigned short)((u + 0x7FFF + ((u >> 16) & 1)) >> 16);
}
__device__ __forceinline__ float bf2f(unsigned short h) {
  return __uint_as_float((unsigned)h << 16);
}

// ---------------------------------------------------------------------------
// Whole-channel scalar weight load (scalar convs 3-4): one asm block, wait
// inside (safe: outputs defined only after the wait).
// ---------------------------------------------------------------------------
template <int N> struct WFull;
template <> struct WFull<8> {            // 72 floats
  f32x16 v0, v1, v2, v3; f32x8 v4;
  __device__ __forceinline__ void load(const float* p) {
    asm volatile(
      "s_load_dwordx16 %0, %5, 0x0\n\t"
      "s_load_dwordx16 %1, %5, 0x40\n\t"
      "s_load_dwordx16 %2, %5, 0x80\n\t"
      "s_load_dwordx16 %3, %5, 0xc0\n\t"
      "s_load_dwordx8  %4, %5, 0x100\n\t"
      "s_waitcnt lgkmcnt(0)"
      : "=&s"(v0), "=&s"(v1), "=&s"(v2), "=&s"(v3), "=&s"(v4)
      : "s"(p));
  }
  __device__ __forceinline__ float get(int i) const {
    return i < 16 ? v0[i] : i < 32 ? v1[i - 16] : i < 48 ? v2[i - 32]
         : i < 64 ? v3[i - 48] : v4[i - 64];
  }
};
template <> struct WFull<6> {            // 54 floats
  f32x16 v0, v1, v2; f32x4 v3; f32x2 v4;
  __device__ __forceinline__ void load(const float* p) {
    asm volatile(
      "s_load_dwordx16 %0, %5, 0x0\n\t"
      "s_load_dwordx16 %1, %5, 0x40\n\t"
      "s_load_dwordx16 %2, %5, 0x80\n\t"
      "s_load_dwordx4  %3, %5, 0xc0\n\t"
      "s_load_dwordx2  %4, %5, 0xd0\n\t"
      "s_waitcnt lgkmcnt(0)"
      : "=&s"(v0), "=&s"(v1), "=&s"(v2), "=&s"(v3), "=&s"(v4)
      : "s"(p));
  }
  __device__ __forceinline__ float get(int i) const {
    return i < 16 ? v0[i] : i < 32 ? v1[i - 16] : i < 48 ? v2[i - 32]
         : i < 52 ? v3[i - 48] : v4[i - 52];
  }
};

// ---------------------------------------------------------------------------
// CSR build, pass 1: 256-bucket histogram of dst>>10
// ---------------------------------------------------------------------------
__global__ __launch_bounds__(256) void k_bhist(const int4* __restrict__ dst,
                                               int* __restrict__ gb) {
  __shared__ int lc[256];
  int t = threadIdx.x;
  lc[t] = 0;
  __syncthreads();
  int base = blockIdx.x * 1024;            // int4 units; 4096 edges/block
#pragma unroll
  for (int q = 0; q < 4; ++q) {
    int4 d = dst[base + q * 256 + t];
    atomicAdd(&lc[d.x >> 10], 1); atomicAdd(&lc[d.y >> 10], 1);
    atomicAdd(&lc[d.z >> 10], 1); atomicAdd(&lc[d.w >> 10], 1);
  }
  __syncthreads();
  atomicAdd(&gb[t], lc[t]);
}

// exclusive scan of 256 bucket counts -> bbase[257]; copy to bcur
__global__ __launch_bounds__(256) void k_bscan(const int* __restrict__ gb,
                                               int* __restrict__ bbase,
                                               int* __restrict__ bcur) {
  __shared__ int sd[256];
  int t = threadIdx.x;
  sd[t] = gb[t];
  __syncthreads();
  for (int off = 1; off < 256; off <<= 1) {
    int v = (t >= off) ? sd[t - off] : 0;
    __syncthreads();
    sd[t] += v;
    __syncthreads();
  }
  int ex = (t == 0) ? 0 : sd[t - 1];
  bbase[t] = ex;
  bcur[t]  = ex;
  if (t == 255) bbase[256] = sd[255];
}

// pass 2: LDS-binned scatter of packed (dstLocal<<18 | src) into bucket runs.
__global__ __launch_bounds__(256) void k_bin(const int4* __restrict__ src4,
                                             const int4* __restrict__ dst4,
                                             int* __restrict__ bcur,
                                             unsigned* __restrict__ pairs) {
  __shared__ int lcnt[256], lofs[256], lcur[256];
  __shared__ unsigned lp[4096];
  int t = threadIdx.x;
  lcnt[t] = 0;
  __syncthreads();
  int base = blockIdx.x * 1024;
  int4 dreg[4], sreg[4];
#pragma unroll
  for (int q = 0; q < 4; ++q) {
    dreg[q] = dst4[base + q * 256 + t];
    sreg[q] = src4[base + q * 256 + t];
  }
#pragma unroll
  for (int q = 0; q < 4; ++q) {
    atomicAdd(&lcnt[dreg[q].x >> 10], 1); atomicAdd(&lcnt[dreg[q].y >> 10], 1);
    atomicAdd(&lcnt[dreg[q].z >> 10], 1); atomicAdd(&lcnt[dreg[q].w >> 10], 1);
  }
  __syncthreads();
  int c = lcnt[t];
  lofs[t] = c;
  __syncthreads();
  for (int off = 1; off < 256; off <<= 1) {
    int v = (t >= off) ? lofs[t - off] : 0;
    __syncthreads();
    lofs[t] += v;
    __syncthreads();
  }
  int myofs = lofs[t] - c;
  lcur[t] = myofs;
  int gb = atomicAdd(&bcur[t], c);
  __syncthreads();
#pragma unroll
  for (int q = 0; q < 4; ++q) {
    int d[4] = {dreg[q].x, dreg[q].y, dreg[q].z, dreg[q].w};
    int s[4] = {sreg[q].x, sreg[q].y, sreg[q].z, sreg[q].w};
#pragma unroll
    for (int j = 0; j < 4; ++j) {
      int pos = atomicAdd(&lcur[d[j] >> 10], 1);
      lp[pos] = ((unsigned)(d[j] & 1023) << 18) | (unsigned)s[j];
    }
  }
  __syncthreads();
  for (int k = 0; k < c; ++k) pairs[gb + k] = lp[myofs + k];
}

// pass 3: per-bucket counting sort. 4-ALIGNED per-node segments at fixed
// bucket stride. Pads (<=3 per node) written precisely = NN (zero row).
__global__ __launch_bounds__(256) void k_bsort(const unsigned* __restrict__ pairs,
                                               const int* __restrict__ bbase,
                                               int* __restrict__ ssrc,
                                               int* __restrict__ offs,
                                               int* __restrict__ dgr,
                                               float* __restrict__ dinv) {
  __shared__ int cnt[1024], ofs[1024], sblk[256];
  int b = blockIdx.x, t = threadIdx.x;
  int s0 = bbase[b], n = bbase[b + 1] - s0;
  int gbase = b * BSTRIDE;
  for (int i = t; i < 1024; i += 256) cnt[i] = 0;
  __syncthreads();
  for (int i = t; i < n; i += 256) {
    unsigned p = pairs[s0 + i];
    atomicAdd(&cnt[p >> 18], 1);
  }
  __syncthreads();
  int l4 = t * 4;
  int c0 = cnt[l4], c1 = cnt[l4 + 1], c2 = cnt[l4 + 2], c3 = cnt[l4 + 3];
  int a0 = (c0 + 3) & ~3, a1 = (c1 + 3) & ~3, a2 = (c2 + 3) & ~3, a3 = (c3 + 3) & ~3;
  int sum = a0 + a1 + a2 + a3;
  sblk[t] = sum;
  __syncthreads();
  for (int off = 1; off < 256; off <<= 1) {
    int v = (t >= off) ? sblk[t - off] : 0;
    __syncthreads();
    sblk[t] += v;
    __syncthreads();
  }
  int ex = sblk[t] - sum;
  int o0 = gbase + ex, o1 = o0 + a0, o2 = o1 + a1, o3 = o2 + a2;
  ofs[l4] = o0; ofs[l4 + 1] = o1; ofs[l4 + 2] = o2; ofs[l4 + 3] = o3;
  int node = b * 1024 + l4;
  *(int4*)&offs[node] = make_int4(o0, o1, o2, o3);
  *(int4*)&dgr[node]  = make_int4(c0, c1, c2, c3);
  *(float4*)&dinv[node] = make_float4(rsqrtf((float)(c0 + 1)),
                                      rsqrtf((float)(c1 + 1)),
                                      rsqrtf((float)(c2 + 1)),
                                      rsqrtf((float)(c3 + 1)));
  for (int p = c0; p < a0; ++p) ssrc[o0 + p] = NN;
  for (int p = c1; p < a1; ++p) ssrc[o1 + p] = NN;
  for (int p = c2; p < a2; ++p) ssrc[o2 + p] = NN;
  for (int p = c3; p < a3; ++p) ssrc[o3 + p] = NN;
  __syncthreads();
  for (int i = t; i < n; i += 256) {
    unsigned p = pairs[s0 + i];
    int pos = atomicAdd(&ofs[p >> 18], 1);
    ssrc[pos] = (int)(p & 0x3FFFFu);
  }
}

// ---------------------------------------------------------------------------
// GCN compute
// ---------------------------------------------------------------------------
__global__ void k_zrows(float* hA, float* hB, float* xs) {
  int t = threadIdx.x;
  if (t < 64) hA[(size_t)NN * 64 + t] = 0.f;
  else if (t < 128) hB[(size_t)NN * 64 + (t - 64)] = 0.f;
  else if (t < 132) xs[(size_t)NN * 4 + (t - 128)] = 0.f;
}

__global__ __launch_bounds__(256) void k_xscale(const float4* __restrict__ x,
                                                const float* __restrict__ dinv,
                                                float4* __restrict__ xs) {
  int i = blockIdx.x * 256 + threadIdx.x;
  float4 v = x[i];
  float d = dinv[i];
  xs[i] = make_float4(v.x * d, v.y * d, v.z * d, v.w * d);
}

__global__ __launch_bounds__(256) void k_agg4(const float4* __restrict__ xs,
                                              const float* __restrict__ dinv,
                                              const int* __restrict__ offs,
                                              const int* __restrict__ dgr,
                                              const int4* __restrict__ ssrc4,
                                              float4* __restrict__ out) {
  for (int i = blockIdx.x * 256 + threadIdx.x; i < NN; i += gridDim.x * 256) {
    float di = dinv[i];
    int k4 = offs[i] >> 2, deg = dgr[i];
    float4 acc = xs[i];
    int t4n = (deg + 3) >> 2;
    int4 s4 = ssrc4[k4];
    for (int t4 = 0; t4 < t4n; ++t4) {
      int4 nx = ssrc4[k4 + t4 + 1];
      float4 v0 = xs[s4.x], v1 = xs[s4.y], v2 = xs[s4.z], v3 = xs[s4.w];
      acc.x += v0.x + v1.x + v2.x + v3.x;
      acc.y += v0.y + v1.y + v2.y + v3.y;
      acc.z += v0.z + v1.z + v2.z + v3.z;
      acc.w += v0.w + v1.w + v2.w + v3.w;
      s4 = nx;
    }
    out[i] = make_float4(acc.x * di, acc.y * di, acc.z * di, acc.w * di);
  }
}

__global__ __launch_bounds__(256) void k_matmul4(const float* __restrict__ h,
                                                 const float* __restrict__ W,
                                                 const float* __restrict__ bias,
                                                 const float* __restrict__ dinv,
                                                 float* __restrict__ out) {
  int lane = threadIdx.x & 63;
  int wv   = threadIdx.x >> 6;
  float w0 = W[lane], w1 = W[64 + lane], w2 = W[128 + lane], w3 = W[192 + lane];
  float bl = bias[lane];
  for (int node = blockIdx.x * 4 + wv; node < NN; node += gridDim.x * 4) {
    float4 hv = *(const float4*)(h + (size_t)node * 4);
    float dn = dinv[node];
    float acc = fmaf(hv.x, w0, fmaf(hv.y, w1, fmaf(hv.z, w2, fmaf(hv.w, w3, bl))));
    out[(size_t)node * 64 + lane] = fmaxf(acc, 0.f) * dn;
  }
}

// Fused GCN layer on pre-scaled rows h'. Dual-block gather; uniform broadcast
// matvec. Matvec W is loaded in TWO 32-register halves per iteration (L1-hot
// reloads) to keep peak VGPR < 64 -> 2x wave occupancy for gather latency
// hiding. Empty reg-tie asm defeats LICM re-hoisting of the W loads.
template <bool SCALE_OUT, bool BF16OUT>
__global__ __launch_bounds__(256) void k_aggW(const float* __restrict__ h,
                                              const float* __restrict__ dinv,
                                              const int* __restrict__ offs,
                                              const int* __restrict__ dgr,
                                              const int4* __restrict__ ssrc4,
                                              const float* __restrict__ W,
                                              const float* __restrict__ bias,
                                              float* __restrict__ out,
                                              unsigned short* __restrict__ xhi,
                                              unsigned short* __restrict__ xlo) {
  __shared__ float g[16][64];
  const float4* h4 = (const float4*)h;
  int lane = threadIdx.x & 63;
  int wv   = threadIdx.x >> 6;
  int sub  = lane >> 4;
  int fl   = lane & 15;
  float bl = bias[lane];

  for (int i0 = (blockIdx.x * 4 + wv) * 4; i0 < NN; i0 += gridDim.x * 16) {
    int i = i0 + sub;
    float di = dinv[i];
    int k4 = offs[i] >> 2;
    int deg = dgr[i];
    int t4n = (deg + 3) >> 2;

    float4 acc  = h4[(size_t)i * 16 + fl];
    float4 accB = make_float4(0.f, 0.f, 0.f, 0.f);
    int4 sA = ssrc4[k4];
    int t4 = 0;
#pragma unroll 1
    for (; t4 + 2 <= t4n; t4 += 2) {
      int4 sB = ssrc4[k4 + t4 + 1];
      int4 nx = ssrc4[k4 + t4 + 2];
      float4 v0 = h4[(size_t)sA.x * 16 + fl];
      float4 v1 = h4[(size_t)sA.y * 16 + fl];
      float4 v2 = h4[(size_t)sA.z * 16 + fl];
      float4 v3 = h4[(size_t)sA.w * 16 + fl];
      float4 u0 = h4[(size_t)sB.x * 16 + fl];
      float4 u1 = h4[(size_t)sB.y * 16 + fl];
      float4 u2 = h4[(size_t)sB.z * 16 + fl];
      float4 u3 = h4[(size_t)sB.w * 16 + fl];
      acc.x  += v0.x + v1.x + v2.x + v3.x;
      acc.y  += v0.y + v1.y + v2.y + v3.y;
      acc.z  += v0.z + v1.z + v2.z + v3.z;
      acc.w  += v0.w + v1.w + v2.w + v3.w;
      accB.x += u0.x + u1.x + u2.x + u3.x;
      accB.y += u0.y + u1.y + u2.y + u3.y;
      accB.z += u0.z + u1.z + u2.z + u3.z;
      accB.w += u0.w + u1.w + u2.w + u3.w;
      sA = nx;
    }
    if (t4 < t4n) {
      float4 v0 = h4[(size_t)sA.x * 16 + fl];
      float4 v1 = h4[(size_t)sA.y * 16 + fl];
      float4 v2 = h4[(size_t)sA.z * 16 + fl];
      float4 v3 = h4[(size_t)sA.w * 16 + fl];
      acc.x += v0.x + v1.x + v2.x + v3.x;
      acc.y += v0.y + v1.y + v2.y + v3.y;
      acc.z += v0.z + v1.z + v2.z + v3.z;
      acc.w += v0.w + v1.w + v2.w + v3.w;
    }
    acc.x += accB.x; acc.y += accB.y; acc.z += accB.z; acc.w += accB.w;

    float4 sacc = make_float4(acc.x * di, acc.y * di, acc.z * di, acc.w * di);
    int row = wv * 4 + sub;
    *(float4*)&g[row][fl * 4] = sacc;
    asm volatile("s_waitcnt lgkmcnt(0)" ::: "memory");

    float o4[4];
#pragma unroll
    for (int n = 0; n < 4; ++n) o4[n] = bl;
    const float* Wp = W;
#pragma unroll 1
    for (int half = 0; half < 2; ++half) {
      asm volatile("" : "+s"(Wp));       // opaque: keep wreg at 32 regs/half
      float wreg[32];
#pragma unroll
      for (int k = 0; k < 32; ++k)
        wreg[k] = Wp[(size_t)(half * 32 + k) * 64 + lane];
#pragma unroll
      for (int n = 0; n < 4; ++n) {
        const float4* gp = (const float4*)&g[wv * 4 + n][half * 32];
        float o = o4[n];
#pragma unroll
        for (int q = 0; q < 8; ++q) {
          float4 gv = gp[q];
          o = fmaf(gv.x, wreg[q * 4 + 0], o);
          o = fmaf(gv.y, wreg[q * 4 + 1], o);
          o = fmaf(gv.z, wreg[q * 4 + 2], o);
          o = fmaf(gv.w, wreg[q * 4 + 3], o);
        }
        o4[n] = o;
      }
    }

#pragma unroll
    for (int n = 0; n < 4; ++n) {
      float val = fmaxf(o4[n], 0.f);
      if constexpr (SCALE_OUT) val *= dinv[i0 + n];
      if constexpr (BF16OUT) {
        size_t b = (size_t)(PADP + i0 + n) * 64 + lane;
        unsigned short hh = f2bf(val);
        xhi[b] = hh;
        xlo[b] = f2bf(val - bf2f(hh));
      } else {
        out[(size_t)(i0 + n) * 64 + lane] = val;
      }
    }
  }
}

// ---------------------------------------------------------------------------
// conv1 MFMA weights repack: idx = ((t*2+ks)*2+nf)*512 + lane*8 + i
//   o = nf*16 + (lane&15); c = ks*32 + (lane>>4)*8 + i; w = cw1[o][c][t]
// ---------------------------------------------------------------------------
__global__ __launch_bounds__(256) void k_wrepm(const float* __restrict__ w,
                                               unsigned short* __restrict__ whim,
                                               unsigned short* __restrict__ wlom) {
  int idx = blockIdx.x * 256 + threadIdx.x;
  if (idx >= 9 * 2 * 2 * 512) return;
  int i  = idx & 7;
  int l  = (idx >> 3) & 63;
  int nf = (idx >> 9) & 1;
  int ks = (idx >> 10) & 1;
  int t  = idx >> 11;
  int o = nf * 16 + (l & 15);
  int c = ks * 32 + (l >> 4) * 8 + i;
  float v = w[(o * 64 + c) * 9 + t];
  unsigned short h = f2bf(v);
  whim[idx] = h;
  wlom[idx] = f2bf(v - bf2f(h));
}

// conv2 MFMA weights repack (K=32, COUT=16): idx = t*512 + lane*8 + i
//   o = lane&15; c = (lane>>4)*8 + i; w = cw2[o][c][t]
__global__ __launch_bounds__(256) void k_wrepm2(const float* __restrict__ w,
                                                unsigned short* __restrict__ whim,
                                                unsigned short* __restrict__ wlom) {
  int idx = blockIdx.x * 256 + threadIdx.x;
  if (idx >= 9 * 512) return;
  int i = idx & 7;
  int l = (idx >> 3) & 63;
  int t = idx >> 9;
  int o = l & 15;
  int c = (l >> 4) * 8 + i;
  float v = w[(o * 32 + c) * 9 + t];
  unsigned short h = f2bf(v);
  whim[idx] = h;
  wlom[idx] = f2bf(v - bf2f(h));
}

// ---------------------------------------------------------------------------
// conv1 (64->32) implicit-GEMM via MFMA, LDS-staged (r14-proven structure).
// Epilogue: channels-last bf16 hi/lo into PADP2-padded arrays for conv2m.
// ---------------------------------------------------------------------------
__global__ __launch_bounds__(256) void k_conv1m(const unsigned short* __restrict__ xhi,
                                                const unsigned short* __restrict__ xlo,
                                                const unsigned short* __restrict__ whim,
                                                const unsigned short* __restrict__ wlom,
                                                const float* __restrict__ cb,
                                                unsigned short* __restrict__ y2hi,
                                                unsigned short* __restrict__ y2lo) {
  constexpr int PXS  = 80;           // bytes per px per half (64 data + 16 skew)
  constexpr int ROWB = 66 * PXS;     // 5280 B per staged row
  constexpr int HALF = 6 * ROWB;     // 31680 B per half (hi | lo)
  __shared__ __align__(16) unsigned char smem[2 * HALF];   // 63360 B

  int tid  = threadIdx.x;
  int lane = tid & 63, wv = tid >> 6;
  int sx = blockIdx.x & 7, gy = blockIdx.x >> 3;   // 8 x-strips, 128 y-groups
  int x0 = sx * 64, y0 = gy * 4;
  int lm = lane & 15, lc = lane >> 4;

  f32x4 acc[4][2];
#pragma unroll
  for (int mf = 0; mf < 4; ++mf)
#pragma unroll
    for (int nf = 0; nf < 2; ++nf) acc[mf][nf] = (f32x4){0.f, 0.f, 0.f, 0.f};

#pragma unroll 1
  for (int ks = 0; ks < 2; ++ks) {
    if (ks) __syncthreads();             // protect prev phase's reads
#pragma unroll 1
    for (int it = 0; it < 13; ++it) {
      int idx = it * 256 + tid;
      if (idx < 3168) {                  // 2 arr x 396 px x 4 chunks
        int arr = idx >= 1584;
        int rem = arr ? idx - 1584 : idx;
        int chunk = rem & 3;
        int pxr = rem >> 2;              // 0..395
        int r = pxr / 66, px = pxr - r * 66;
        int xx = x0 - 1 + px;
        uint4 v = make_uint4(0u, 0u, 0u, 0u);
        if (xx >= 0 && xx < GS) {
          size_t p = (size_t)(PADP + (y0 - 1 + r) * GS + xx);
          const unsigned short* src = arr ? xlo : xhi;
          v = *(const uint4*)((const unsigned char*)src + p * 128 + ks * 64 + chunk * 16);
        }
        *(uint4*)(smem + arr * HALF + r * ROWB + px * PXS + chunk * 16) = v;
      }
    }
    __syncthreads();
#pragma unroll 1
    for (int t = 0; t < 9; ++t) {
      int ky = t / 3, kx = t % 3;
      const unsigned short* wb = whim + (size_t)(((t * 2 + ks) * 2) * 64 + lane) * 8;
      const unsigned short* wl = wlom + (size_t)(((t * 2 + ks) * 2) * 64 + lane) * 8;
      s16x8 bh0 = *(const s16x8*)(wb);
      s16x8 bh1 = *(const s16x8*)(wb + 512);
      s16x8 bl0 = *(const s16x8*)(wl);
      s16x8 bl1 = *(const s16x8*)(wl + 512);
      int r = wv + ky;
#pragma unroll
      for (int mf = 0; mf < 4; ++mf) {
        int px = mf * 16 + lm + kx;
        const unsigned char* ap = smem + r * ROWB + px * PXS + lc * 16;
        s16x8 ah = *(const s16x8*)(ap);
        s16x8 al = *(const s16x8*)(ap + HALF);
        acc[mf][0] = __builtin_amdgcn_mfma_f32_16x16x32_bf16(ah, bh0, acc[mf][0], 0, 0, 0);
        acc[mf][0] = __builtin_amdgcn_mfma_f32_16x16x32_bf16(ah, bl0, acc[mf][0], 0, 0, 0);
        acc[mf][0] = __builtin_amdgcn_mfma_f32_16x16x32_bf16(al, bh0, acc[mf][0], 0, 0, 0);
        acc[mf][1] = __builtin_amdgcn_mfma_f32_16x16x32_bf16(ah, bh1, acc[mf][1], 0, 0, 0);
        acc[mf][1] = __builtin_amdgcn_mfma_f32_16x16x32_bf16(ah, bl1, acc[mf][1], 0, 0, 0);
        acc[mf][1] = __builtin_amdgcn_mfma_f32_16x16x32_bf16(al, bh1, acc[mf][1], 0, 0, 0);
      }
    }
  }
  __syncthreads();                       // all staged reads done; reuse LDS

  // epilogue: pixel-major via LDS -> channels-last bf16 hi/lo (+bias, relu)
  float* lds = (float*)smem;             // [4][64][33] floats = 33792 B
#pragma unroll
  for (int mf = 0; mf < 4; ++mf)
#pragma unroll
    for (int nf = 0; nf < 2; ++nf)
#pragma unroll
      for (int r = 0; r < 4; ++r)
        lds[((wv * 64 + mf * 16 + lc * 4 + r) * 33) + nf * 16 + lm] = acc[mf][nf][r];
  asm volatile("s_waitcnt lgkmcnt(0)" ::: "memory");

  size_t pp = (size_t)PADP2 + (size_t)(y0 + wv) * GS + x0 + lane;
  unsigned uh[16], ul[16];
#pragma unroll
  for (int o2 = 0; o2 < 16; ++o2) {
    float v0 = fmaxf(lds[(wv * 64 + lane) * 33 + 2 * o2]     + cb[2 * o2],     0.f);
    float v1 = fmaxf(lds[(wv * 64 + lane) * 33 + 2 * o2 + 1] + cb[2 * o2 + 1], 0.f);
    unsigned short h0 = f2bf(v0), h1 = f2bf(v1);
    unsigned short l0 = f2bf(v0 - bf2f(h0)), l1 = f2bf(v1 - bf2f(h1));
    uh[o2] = (unsigned)h0 | ((unsigned)h1 << 16);
    ul[o2] = (unsigned)l0 | ((unsigned)l1 << 16);
  }
  uint4* dh = (uint4*)(y2hi + pp * 32);
  uint4* dl = (uint4*)(y2lo + pp * 32);
#pragma unroll
  for (int q = 0; q < 4; ++q) {
    dh[q] = make_uint4(uh[q * 4], uh[q * 4 + 1], uh[q * 4 + 2], uh[q * 4 + 3]);
    dl[q] = make_uint4(ul[q * 4], ul[q * 4 + 1], ul[q * 4 + 2], ul[q * 4 + 3]);
  }
}

// ---------------------------------------------------------------------------
// conv2 (32->16) implicit-GEMM via MFMA: clone of conv1m, K=32 (one phase),
// COUT=16 (one nf). Output planar fp32 for the scalar conv3.
// ---------------------------------------------------------------------------
__global__ __launch_bounds__(256) void k_conv2m(const unsigned short* __restrict__ y2hi,
                                                const unsigned short* __restrict__ y2lo,
                                                const unsigned short* __restrict__ whim,
                                                const unsigned short* __restrict__ wlom,
                                                const float* __restrict__ cb,
                                                float* __restrict__ outp) {
  constexpr int PXS  = 80;           // 64 B data (32ch bf16) + 16 skew
  constexpr int ROWB = 66 * PXS;
  constexpr int HALF = 6 * ROWB;
  __shared__ __align__(16) unsigned char smem[2 * HALF];

  int tid  = threadIdx.x;
  int lane = tid & 63, wv = tid >> 6;
  int sx = blockIdx.x & 7, gy = blockIdx.x >> 3;
  int x0 = sx * 64, y0 = gy * 4;
  int lm = lane & 15, lc = lane >> 4;

  f32x4 acc[4];
#pragma unroll
  for (int mf = 0; mf < 4; ++mf) acc[mf] = (f32x4){0.f, 0.f, 0.f, 0.f};

  // stage: 6 rows x 66 px x 32 ch, hi+lo
#pragma unroll 1
  for (int it = 0; it < 13; ++it) {
    int idx = it * 256 + tid;
    if (idx < 3168) {
      int arr = idx >= 1584;
      int rem = arr ? idx - 1584 : idx;
      int chunk = rem & 3;
      int pxr = rem >> 2;
      int r = pxr / 66, px = pxr - r * 66;
      int xx = x0 - 1 + px;
      uint4 v = make_uint4(0u, 0u, 0u, 0u);
      if (xx >= 0 && xx < GS) {
        size_t p = (size_t)(PADP2 + (y0 - 1 + r) * GS + xx);
        const unsigned short* src = arr ? y2lo : y2hi;
        v = *(const uint4*)((const unsigned char*)src + p * 64 + chunk * 16);
      }
      *(uint4*)(smem + arr * HALF + r * ROWB + px * PXS + chunk * 16) = v;
    }
  }
  __syncthreads();
#pragma unroll 1
  for (int t = 0; t < 9; ++t) {
    int ky = t / 3, kx = t % 3;
    s16x8 bh = *(const s16x8*)(whim + ((size_t)t * 64 + lane) * 8);
    s16x8 bl = *(const s16x8*)(wlom + ((size_t)t * 64 + lane) * 8);
    int r = wv + ky;
#pragma unroll
    for (int mf = 0; mf < 4; ++mf) {
      int px = mf * 16 + lm + kx;
      const unsigned char* ap = smem + r * ROWB + px * PXS + lc * 16;
      s16x8 ah = *(const s16x8*)(ap);
      s16x8 al = *(const s16x8*)(ap + HALF);
      acc[mf] = __builtin_amdgcn_mfma_f32_16x16x32_bf16(ah, bh, acc[mf], 0, 0, 0);
      acc[mf] = __builtin_amdgcn_mfma_f32_16x16x32_bf16(ah, bl, acc[mf], 0, 0, 0);
      acc[mf] = __builtin_amdgcn_mfma_f32_16x16x32_bf16(al, bh, acc[mf], 0, 0, 0);
    }
  }
  __syncthreads();

  // epilogue: pixel-major via LDS -> planar fp32 + bias + relu
  float* lds = (float*)smem;             // [4][64][17] floats = 17408 B
#pragma unroll
  for (int mf = 0; mf < 4; ++mf)
#pragma unroll
    for (int r = 0; r < 4; ++r)
      lds[((wv * 64 + mf * 16 + lc * 4 + r) * 17) + lm] = acc[mf][r];
  asm volatile("s_waitcnt lgkmcnt(0)" ::: "memory");

  size_t ob = (size_t)(y0 + wv) * GS + x0 + lane;
#pragma unroll
  for (int o = 0; o < 16; ++o) {
    float v = lds[((wv * 64 + lane) * 17) + o] + cb[o];
    outp[(size_t)o * P + ob] = fmaxf(v, 0.f);
  }
}

// Repack conv weights OIHW -> group-major [g][c][tap][o_in_group]
template <int CIN, int COUT, int COUTB>
__global__ __launch_bounds__(256) void k_wrep(const float* __restrict__ w,
                                              float* __restrict__ wr) {
  int i = blockIdx.x * 256 + threadIdx.x;
  if (i >= CIN * 9 * COUT) return;
  int ol = i % COUTB;
  int t  = (i / COUTB) % 9;
  int c  = (i / (COUTB * 9)) % CIN;
  int g  = i / (COUTB * 9 * CIN);
  wr[i] = w[(((g * COUTB + ol) * CIN) + c) * 9 + t];
}

// ---------------------------------------------------------------------------
// Planar scalar 3x3 conv (layers 3-4), r10-proven config.
// ---------------------------------------------------------------------------
template <int CIN, int COUTB, bool RELU>
__global__ __launch_bounds__(256) void k_conv(const float* __restrict__ in,
                                              const float* __restrict__ wrep,
                                              const float* __restrict__ cb,
                                              float* __restrict__ out) {
  int tx = threadIdx.x;
  int ty = threadIdx.y;
  int g  = blockIdx.z;
  int x0 = (blockIdx.x * 64 + tx) * 2;
  int y  = blockIdx.y * 4 + ty;

  float acc0[COUTB], acc1[COUTB];
#pragma unroll
  for (int o = 0; o < COUTB; ++o) { acc0[o] = 0.f; acc1[o] = 0.f; }

  bool xlo = x0 > 0;
  bool xhi = x0 < GS - 2;
  int rok[3], yoff[3];
#pragma unroll
  for (int r = 0; r < 3; ++r) {
    int yy = y + r - 1;
    rok[r] = (yy >= 0) && (yy < GS);
    int yc = yy < 0 ? 0 : (yy > GS - 1 ? GS - 1 : yy);
    yoff[r] = yc * GS;
  }
  const float* wg = wrep + (size_t)g * CIN * 9 * COUTB;

  WFull<COUTB> w;
#pragma unroll 1
  for (int c = 0; c < CIN; ++c) {
    float iv[3][4];
#pragma unroll
    for (int r = 0; r < 3; ++r) {
      const float* ip = in + (size_t)c * P + yoff[r] + x0;
      if (rok[r]) {
        float2 m = *(const float2*)ip;
        iv[r][1] = m.x; iv[r][2] = m.y;
        iv[r][0] = xlo ? ip[-1] : 0.f;
        iv[r][3] = xhi ? ip[2]  : 0.f;
      } else {
        iv[r][0] = iv[r][1] = iv[r][2] = iv[r][3] = 0.f;
      }
    }
    w.load(wg + (size_t)c * 9 * COUTB);
#pragma unroll
    for (int t9 = 0; t9 < 9; ++t9) {
      int ky = t9 / 3, kx = t9 % 3;
      float a = iv[ky][kx], b2 = iv[ky][kx + 1];
#pragma unroll
      for (int o = 0; o < COUTB; ++o) {
        float wv = w.get(t9 * COUTB + o);
        acc0[o] = fmaf(a, wv, acc0[o]);
        acc1[o] = fmaf(b2, wv, acc1[o]);
      }
    }
  }

  size_t obase = (size_t)(g * COUTB) * P + (size_t)y * GS + x0;
#pragma unroll
  for (int o = 0; o < COUTB; ++o) {
    float bv = cb[g * COUTB + o];
    float v0 = acc0[o] + bv;
    float v1 = acc1[o] + bv;
    if (RELU) { v0 = fmaxf(v0, 0.f); v1 = fmaxf(v1, 0.f); }
    *(float2*)&out[obase + (size_t)o * P] = make_float2(v0, v1);
  }
}

// ---------------------------------------------------------------------------
extern "C" void kernel_launch(void* const* d_in, const int* in_sizes, int n_in,
                              void* d_out, int out_size, void* d_ws, size_t ws_size,
                              hipStream_t stream) {
  const float* x   = (const float*)d_in[0];
  const int*   esr = (const int*)d_in[1];
  const int*   eds = (const int*)d_in[2];
  const float* W1  = (const float*)d_in[4];
  const float* b1  = (const float*)d_in[5];
  const float* W2  = (const float*)d_in[6];
  const float* b2  = (const float*)d_in[7];
  const float* W3  = (const float*)d_in[8];
  const float* b3  = (const float*)d_in[9];
  const float* cw1 = (const float*)d_in[10];
  const float* cb1 = (const float*)d_in[11];
  const float* cw2 = (const float*)d_in[12];
  const float* cb2 = (const float*)d_in[13];
  const float* cw3 = (const float*)d_in[14];
  const float* cb3 = (const float*)d_in[15];
  const float* cw4 = (const float*)d_in[16];
  const float* cb4 = (const float*)d_in[17];
  float* out = (float*)d_out;

  char* ws = (char*)d_ws;
  const size_t MB = 1 << 20;
  const size_t KB = 1 << 10;
  const size_t XBYTES = (size_t)(P + 2 * PADP) * 64 * 2;   // 33,816,576
  // Region A [0,65MB): pairs -> xs -> hA(h1') -> {Xhi,Xlo} -> conv2out(16MB)
  unsigned*        pairs = (unsigned*)(ws);
  float*           xs    = (float*)(ws);
  float*           hA    = (float*)(ws);                    // h1' (64MB)
  unsigned short*  xhi   = (unsigned short*)(ws);           // 32.25MB
  unsigned short*  xlo   = (unsigned short*)(ws + XBYTES);  // 32.25MB
  float*           cA    = (float*)(ws);                    // conv2m out (16MB)
  // Region B [65MB,130MB): xagg -> hB(h2') -> {y2hi,y2lo} -> conv3out(8MB)
  float*           xagg  = (float*)(ws + 65 * MB);
  float*           hB    = (float*)(ws + 65 * MB);          // h2' (64MB+row)
  unsigned short*  y2hi  = (unsigned short*)(ws + 65 * MB); // 16.9MB
  unsigned short*  y2lo  = (unsigned short*)(ws + 83 * MB); // 16.9MB
  float*           cB8   = (float*)(ws + 101 * MB);         // conv3 out (8MB)
  int*             ssrc  = (int*)(ws + 130 * MB);
  float*           dinv  = (float*)(ws + 142 * MB + 8 * KB);
  int*             dgr   = (int*)(ws + 143 * MB + 16 * KB);
  int*             offs  = (int*)(ws + 144 * MB + 24 * KB);
  int*             gb    = (int*)(ws + 145 * MB + 32 * KB);
  int*             bbase = (int*)(ws + 145 * MB + 36 * KB);
  int*             bcur  = (int*)(ws + 145 * MB + 40 * KB);
  unsigned short*  whim  = (unsigned short*)(ws + 145 * MB + 48 * KB);   // 36KB
  unsigned short*  wlom  = (unsigned short*)(ws + 145 * MB + 88 * KB);   // 36KB
  float*           wr3   = (float*)(ws + 145 * MB + 128 * KB);           // 4.5KB
  float*           wr4   = wr3 + 16 * 9 * 8;                             // 1.7KB
  unsigned short*  whim2 = (unsigned short*)(ws + 145 * MB + 160 * KB);  // 9KB
  unsigned short*  wlom2 = (unsigned short*)(ws + 145 * MB + 176 * KB);  // 9KB

  // ---- weight repacks ----
  k_wrepm<<<72, 256, 0, stream>>>(cw1, whim, wlom);
  k_wrepm2<<<18, 256, 0, stream>>>(cw2, whim2, wlom2);
  k_wrep<16,  8, 8><<<(16 * 9 *  8 + 255) / 256, 256, 0, stream>>>(cw3, wr3);
  k_wrep< 8,  6, 6><<<( 8 * 9 *  6 + 255) / 256, 256, 0, stream>>>(cw4, wr4);

  // ---- CSR build ----
  hipMemsetAsync(gb, 0, 256 * sizeof(int), stream);
  k_bhist<<<512, 256, 0, stream>>>((const int4*)eds, gb);
  k_bscan<<<1, 256, 0, stream>>>(gb, bbase, bcur);
  k_bin<<<512, 256, 0, stream>>>((const int4*)esr, (const int4*)eds, bcur, pairs);
  k_bsort<<<256, 256, 0, stream>>>(pairs, bbase, ssrc, offs, dgr, dinv);

  // ---- GCN ----
  k_zrows<<<1, 256, 0, stream>>>(hA, hB, xs);
  k_xscale<<<NN / 256, 256, 0, stream>>>((const float4*)x, dinv, (float4*)xs);
  k_agg4<<<1024, 256, 0, stream>>>((const float4*)xs, dinv, offs, dgr,
                                   (const int4*)ssrc, (float4*)xagg);
  k_matmul4<<<2048, 256, 0, stream>>>(xagg, W1, b1, dinv, hA);
  k_aggW<true, false><<<2048, 256, 0, stream>>>(hA, dinv, offs, dgr,
                                                (const int4*)ssrc, W2, b2, hB,
                                                nullptr, nullptr);
  // zero the X pads (h1' region dead), then layer 3 -> bf16 hi/lo
  const size_t PADB = (size_t)PADP * 64 * 2;               // 128KB
  hipMemsetAsync((char*)xhi, 0, PADB, stream);
  hipMemsetAsync((char*)xhi + (size_t)(PADP + P) * 128, 0, PADB, stream);
  hipMemsetAsync((char*)xlo, 0, PADB, stream);
  hipMemsetAsync((char*)xlo + (size_t)(PADP + P) * 128, 0, PADB, stream);
  k_aggW<false, true><<<2048, 256, 0, stream>>>(hB, dinv, offs, dgr,
                                                (const int4*)ssrc, W3, b3, hB,
                                                xhi, xlo);

  // ---- CNN ----
  // y2 pads (hB dead after layer 3)
  const size_t PADB2 = (size_t)PADP2 * 32 * 2;             // 64KB
  hipMemsetAsync((char*)y2hi, 0, PADB2, stream);
  hipMemsetAsync((char*)y2hi + (size_t)(PADP2 + P) * 64, 0, PADB2, stream);
  hipMemsetAsync((char*)y2lo, 0, PADB2, stream);
  hipMemsetAsync((char*)y2lo + (size_t)(PADP2 + P) * 64, 0, PADB2, stream);
  k_conv1m<<<1024, 256, 0, stream>>>(xhi, xlo, whim, wlom, cb1, y2hi, y2lo);
  k_conv2m<<<1024, 256, 0, stream>>>(y2hi, y2lo, whim2, wlom2, cb2, cA);
  k_conv<16, 8, true ><<<dim3(4, 128, 1), dim3(64, 4), 0, stream>>>(cA, wr3, cb3, cB8);
  k_conv< 8, 6, false><<<dim3(4, 128, 1), dim3(64, 4), 0, stream>>>(cB8, wr4, cb4, out);
}

// Round 20
// 423.362 us; speedup vs baseline: 1.0997x; 1.0997x over previous
//
#include <hip/hip_runtime.h>

// Problem constants (fixed by the reference: N = 512*512, E = N*8, grid 512)
#define NN 262144
#define NE 2097152
constexpr int GS = 512;
constexpr int P  = GS * GS;   // == NN
constexpr int BSTRIDE = 12288; // per-bucket ssrc slot stride (4-aligned segs)
constexpr int PADP = 1024;     // pixel-row zero pad for conv1 MFMA gathers
constexpr int PADP2 = 1024;    // pixel-row zero pad for conv2 MFMA gathers

typedef __attribute__((ext_vector_type(16))) float f32x16;
typedef __attribute__((ext_vector_type(8)))  float f32x8;
typedef __attribute__((ext_vector_type(4)))  float f32x4;
typedef __attribute__((ext_vector_type(2)))  float f32x2;
typedef __attribute__((ext_vector_type(8)))  short s16x8;   // bf16x8 MFMA frag

__device__ __forceinline__ unsigned short f2bf(float f) {   // RNE fp32->bf16
  unsigned u = __float_as_uint(f);
  return (unsigned short)((u + 0x7FFF + ((u >> 16) & 1)) >> 16);
}
__device__ __forceinline__ float bf2f(unsigned short h) {
  return __uint_as_float((unsigned)h << 16);
}

// ---------------------------------------------------------------------------
// Whole-channel scalar weight load (scalar convs 3-4): one asm block, wait
// inside (safe: outputs defined only after the wait).
// ---------------------------------------------------------------------------
template <int N> struct WFull;
template <> struct WFull<8> {            // 72 floats
  f32x16 v0, v1, v2, v3; f32x8 v4;
  __device__ __forceinline__ void load(const float* p) {
    asm volatile(
      "s_load_dwordx16 %0, %5, 0x0\n\t"
      "s_load_dwordx16 %1, %5, 0x40\n\t"
      "s_load_dwordx16 %2, %5, 0x80\n\t"
      "s_load_dwordx16 %3, %5, 0xc0\n\t"
      "s_load_dwordx8  %4, %5, 0x100\n\t"
      "s_waitcnt lgkmcnt(0)"
      : "=&s"(v0), "=&s"(v1), "=&s"(v2), "=&s"(v3), "=&s"(v4)
      : "s"(p));
  }
  __device__ __forceinline__ float get(int i) const {
    return i < 16 ? v0[i] : i < 32 ? v1[i - 16] : i < 48 ? v2[i - 32]
         : i < 64 ? v3[i - 48] : v4[i - 64];
  }
};
template <> struct WFull<6> {            // 54 floats
  f32x16 v0, v1, v2; f32x4 v3; f32x2 v4;
  __device__ __forceinline__ void load(const float* p) {
    asm volatile(
      "s_load_dwordx16 %0, %5, 0x0\n\t"
      "s_load_dwordx16 %1, %5, 0x40\n\t"
      "s_load_dwordx16 %2, %5, 0x80\n\t"
      "s_load_dwordx4  %3, %5, 0xc0\n\t"
      "s_load_dwordx2  %4, %5, 0xd0\n\t"
      "s_waitcnt lgkmcnt(0)"
      : "=&s"(v0), "=&s"(v1), "=&s"(v2), "=&s"(v3), "=&s"(v4)
      : "s"(p));
  }
  __device__ __forceinline__ float get(int i) const {
    return i < 16 ? v0[i] : i < 32 ? v1[i - 16] : i < 48 ? v2[i - 32]
         : i < 52 ? v3[i - 48] : v4[i - 52];
  }
};

// ---------------------------------------------------------------------------
// CSR build, pass 1: 256-bucket histogram of dst>>10
// ---------------------------------------------------------------------------
__global__ __launch_bounds__(256) void k_bhist(const int4* __restrict__ dst,
                                               int* __restrict__ gb) {
  __shared__ int lc[256];
  int t = threadIdx.x;
  lc[t] = 0;
  __syncthreads();
  int base = blockIdx.x * 1024;            // int4 units; 4096 edges/block
#pragma unroll
  for (int q = 0; q < 4; ++q) {
    int4 d = dst[base + q * 256 + t];
    atomicAdd(&lc[d.x >> 10], 1); atomicAdd(&lc[d.y >> 10], 1);
    atomicAdd(&lc[d.z >> 10], 1); atomicAdd(&lc[d.w >> 10], 1);
  }
  __syncthreads();
  atomicAdd(&gb[t], lc[t]);
}

// exclusive scan of 256 bucket counts -> bbase[257]; copy to bcur
__global__ __launch_bounds__(256) void k_bscan(const int* __restrict__ gb,
                                               int* __restrict__ bbase,
                                               int* __restrict__ bcur) {
  __shared__ int sd[256];
  int t = threadIdx.x;
  sd[t] = gb[t];
  __syncthreads();
  for (int off = 1; off < 256; off <<= 1) {
    int v = (t >= off) ? sd[t - off] : 0;
    __syncthreads();
    sd[t] += v;
    __syncthreads();
  }
  int ex = (t == 0) ? 0 : sd[t - 1];
  bbase[t] = ex;
  bcur[t]  = ex;
  if (t == 255) bbase[256] = sd[255];
}

// pass 2: LDS-binned scatter of packed (dstLocal<<18 | src) into bucket runs.
__global__ __launch_bounds__(256) void k_bin(const int4* __restrict__ src4,
                                             const int4* __restrict__ dst4,
                                             int* __restrict__ bcur,
                                             unsigned* __restrict__ pairs) {
  __shared__ int lcnt[256], lofs[256], lcur[256];
  __shared__ unsigned lp[4096];
  int t = threadIdx.x;
  lcnt[t] = 0;
  __syncthreads();
  int base = blockIdx.x * 1024;
  int4 dreg[4], sreg[4];
#pragma unroll
  for (int q = 0; q < 4; ++q) {
    dreg[q] = dst4[base + q * 256 + t];
    sreg[q] = src4[base + q * 256 + t];
  }
#pragma unroll
  for (int q = 0; q < 4; ++q) {
    atomicAdd(&lcnt[dreg[q].x >> 10], 1); atomicAdd(&lcnt[dreg[q].y >> 10], 1);
    atomicAdd(&lcnt[dreg[q].z >> 10], 1); atomicAdd(&lcnt[dreg[q].w >> 10], 1);
  }
  __syncthreads();
  int c = lcnt[t];
  lofs[t] = c;
  __syncthreads();
  for (int off = 1; off < 256; off <<= 1) {
    int v = (t >= off) ? lofs[t - off] : 0;
    __syncthreads();
    lofs[t] += v;
    __syncthreads();
  }
  int myofs = lofs[t] - c;
  lcur[t] = myofs;
  int gb = atomicAdd(&bcur[t], c);
  __syncthreads();
#pragma unroll
  for (int q = 0; q < 4; ++q) {
    int d[4] = {dreg[q].x, dreg[q].y, dreg[q].z, dreg[q].w};
    int s[4] = {sreg[q].x, sreg[q].y, sreg[q].z, sreg[q].w};
#pragma unroll
    for (int j = 0; j < 4; ++j) {
      int pos = atomicAdd(&lcur[d[j] >> 10], 1);
      lp[pos] = ((unsigned)(d[j] & 1023) << 18) | (unsigned)s[j];
    }
  }
  __syncthreads();
  for (int k = 0; k < c; ++k) pairs[gb + k] = lp[myofs + k];
}

// pass 3: per-bucket counting sort. 4-ALIGNED per-node segments at fixed
// bucket stride. Pads (<=3 per node) written precisely = NN (zero row).
__global__ __launch_bounds__(256) void k_bsort(const unsigned* __restrict__ pairs,
                                               const int* __restrict__ bbase,
                                               int* __restrict__ ssrc,
                                               int* __restrict__ offs,
                                               int* __restrict__ dgr,
                                               float* __restrict__ dinv) {
  __shared__ int cnt[1024], ofs[1024], sblk[256];
  int b = blockIdx.x, t = threadIdx.x;
  int s0 = bbase[b], n = bbase[b + 1] - s0;
  int gbase = b * BSTRIDE;
  for (int i = t; i < 1024; i += 256) cnt[i] = 0;
  __syncthreads();
  for (int i = t; i < n; i += 256) {
    unsigned p = pairs[s0 + i];
    atomicAdd(&cnt[p >> 18], 1);
  }
  __syncthreads();
  int l4 = t * 4;
  int c0 = cnt[l4], c1 = cnt[l4 + 1], c2 = cnt[l4 + 2], c3 = cnt[l4 + 3];
  int a0 = (c0 + 3) & ~3, a1 = (c1 + 3) & ~3, a2 = (c2 + 3) & ~3, a3 = (c3 + 3) & ~3;
  int sum = a0 + a1 + a2 + a3;
  sblk[t] = sum;
  __syncthreads();
  for (int off = 1; off < 256; off <<= 1) {
    int v = (t >= off) ? sblk[t - off] : 0;
    __syncthreads();
    sblk[t] += v;
    __syncthreads();
  }
  int ex = sblk[t] - sum;
  int o0 = gbase + ex, o1 = o0 + a0, o2 = o1 + a1, o3 = o2 + a2;
  ofs[l4] = o0; ofs[l4 + 1] = o1; ofs[l4 + 2] = o2; ofs[l4 + 3] = o3;
  int node = b * 1024 + l4;
  *(int4*)&offs[node] = make_int4(o0, o1, o2, o3);
  *(int4*)&dgr[node]  = make_int4(c0, c1, c2, c3);
  *(float4*)&dinv[node] = make_float4(rsqrtf((float)(c0 + 1)),
                                      rsqrtf((float)(c1 + 1)),
                                      rsqrtf((float)(c2 + 1)),
                                      rsqrtf((float)(c3 + 1)));
  for (int p = c0; p < a0; ++p) ssrc[o0 + p] = NN;
  for (int p = c1; p < a1; ++p) ssrc[o1 + p] = NN;
  for (int p = c2; p < a2; ++p) ssrc[o2 + p] = NN;
  for (int p = c3; p < a3; ++p) ssrc[o3 + p] = NN;
  __syncthreads();
  for (int i = t; i < n; i += 256) {
    unsigned p = pairs[s0 + i];
    int pos = atomicAdd(&ofs[p >> 18], 1);
    ssrc[pos] = (int)(p & 0x3FFFFu);
  }
}

// ---------------------------------------------------------------------------
// GCN compute
// ---------------------------------------------------------------------------
__global__ void k_zrows(float* hA, float* hB, float* xs) {
  int t = threadIdx.x;
  if (t < 64) hA[(size_t)NN * 64 + t] = 0.f;
  else if (t < 128) hB[(size_t)NN * 64 + (t - 64)] = 0.f;
  else if (t < 132) xs[(size_t)NN * 4 + (t - 128)] = 0.f;
}

__global__ __launch_bounds__(256) void k_xscale(const float4* __restrict__ x,
                                                const float* __restrict__ dinv,
                                                float4* __restrict__ xs) {
  int i = blockIdx.x * 256 + threadIdx.x;
  float4 v = x[i];
  float d = dinv[i];
  xs[i] = make_float4(v.x * d, v.y * d, v.z * d, v.w * d);
}

__global__ __launch_bounds__(256) void k_agg4(const float4* __restrict__ xs,
                                              const float* __restrict__ dinv,
                                              const int* __restrict__ offs,
                                              const int* __restrict__ dgr,
                                              const int4* __restrict__ ssrc4,
                                              float4* __restrict__ out) {
  for (int i = blockIdx.x * 256 + threadIdx.x; i < NN; i += gridDim.x * 256) {
    float di = dinv[i];
    int k4 = offs[i] >> 2, deg = dgr[i];
    float4 acc = xs[i];
    int t4n = (deg + 3) >> 2;
    int4 s4 = ssrc4[k4];
    for (int t4 = 0; t4 < t4n; ++t4) {
      int4 nx = ssrc4[k4 + t4 + 1];
      float4 v0 = xs[s4.x], v1 = xs[s4.y], v2 = xs[s4.z], v3 = xs[s4.w];
      acc.x += v0.x + v1.x + v2.x + v3.x;
      acc.y += v0.y + v1.y + v2.y + v3.y;
      acc.z += v0.z + v1.z + v2.z + v3.z;
      acc.w += v0.w + v1.w + v2.w + v3.w;
      s4 = nx;
    }
    out[i] = make_float4(acc.x * di, acc.y * di, acc.z * di, acc.w * di);
  }
}

__global__ __launch_bounds__(256) void k_matmul4(const float* __restrict__ h,
                                                 const float* __restrict__ W,
                                                 const float* __restrict__ bias,
                                                 const float* __restrict__ dinv,
                                                 float* __restrict__ out) {
  int lane = threadIdx.x & 63;
  int wv   = threadIdx.x >> 6;
  float w0 = W[lane], w1 = W[64 + lane], w2 = W[128 + lane], w3 = W[192 + lane];
  float bl = bias[lane];
  for (int node = blockIdx.x * 4 + wv; node < NN; node += gridDim.x * 4) {
    float4 hv = *(const float4*)(h + (size_t)node * 4);
    float dn = dinv[node];
    float acc = fmaf(hv.x, w0, fmaf(hv.y, w1, fmaf(hv.z, w2, fmaf(hv.w, w3, bl))));
    out[(size_t)node * 64 + lane] = fmaxf(acc, 0.f) * dn;
  }
}

// Fused GCN layer on pre-scaled rows h'. Dual-block gather; uniform broadcast
// matvec with full per-lane W in VGPRs (r18-proven best).
template <bool SCALE_OUT, bool BF16OUT>
__global__ __launch_bounds__(256) void k_aggW(const float* __restrict__ h,
                                              const float* __restrict__ dinv,
                                              const int* __restrict__ offs,
                                              const int* __restrict__ dgr,
                                              const int4* __restrict__ ssrc4,
                                              const float* __restrict__ W,
                                              const float* __restrict__ bias,
                                              float* __restrict__ out,
                                              unsigned short* __restrict__ xhi,
                                              unsigned short* __restrict__ xlo) {
  __shared__ float g[16][64];
  const float4* h4 = (const float4*)h;
  int lane = threadIdx.x & 63;
  int wv   = threadIdx.x >> 6;
  int sub  = lane >> 4;
  int fl   = lane & 15;
  float wreg[64];
#pragma unroll
  for (int k = 0; k < 64; ++k) wreg[k] = W[(size_t)k * 64 + lane];
  float bl = bias[lane];

  for (int i0 = (blockIdx.x * 4 + wv) * 4; i0 < NN; i0 += gridDim.x * 16) {
    int i = i0 + sub;
    float di = dinv[i];
    int k4 = offs[i] >> 2;
    int deg = dgr[i];
    int t4n = (deg + 3) >> 2;

    float4 acc  = h4[(size_t)i * 16 + fl];
    float4 accB = make_float4(0.f, 0.f, 0.f, 0.f);
    int4 sA = ssrc4[k4];
    int t4 = 0;
#pragma unroll 1
    for (; t4 + 2 <= t4n; t4 += 2) {
      int4 sB = ssrc4[k4 + t4 + 1];
      int4 nx = ssrc4[k4 + t4 + 2];
      float4 v0 = h4[(size_t)sA.x * 16 + fl];
      float4 v1 = h4[(size_t)sA.y * 16 + fl];
      float4 v2 = h4[(size_t)sA.z * 16 + fl];
      float4 v3 = h4[(size_t)sA.w * 16 + fl];
      float4 u0 = h4[(size_t)sB.x * 16 + fl];
      float4 u1 = h4[(size_t)sB.y * 16 + fl];
      float4 u2 = h4[(size_t)sB.z * 16 + fl];
      float4 u3 = h4[(size_t)sB.w * 16 + fl];
      acc.x  += v0.x + v1.x + v2.x + v3.x;
      acc.y  += v0.y + v1.y + v2.y + v3.y;
      acc.z  += v0.z + v1.z + v2.z + v3.z;
      acc.w  += v0.w + v1.w + v2.w + v3.w;
      accB.x += u0.x + u1.x + u2.x + u3.x;
      accB.y += u0.y + u1.y + u2.y + u3.y;
      accB.z += u0.z + u1.z + u2.z + u3.z;
      accB.w += u0.w + u1.w + u2.w + u3.w;
      sA = nx;
    }
    if (t4 < t4n) {
      float4 v0 = h4[(size_t)sA.x * 16 + fl];
      float4 v1 = h4[(size_t)sA.y * 16 + fl];
      float4 v2 = h4[(size_t)sA.z * 16 + fl];
      float4 v3 = h4[(size_t)sA.w * 16 + fl];
      acc.x += v0.x + v1.x + v2.x + v3.x;
      acc.y += v0.y + v1.y + v2.y + v3.y;
      acc.z += v0.z + v1.z + v2.z + v3.z;
      acc.w += v0.w + v1.w + v2.w + v3.w;
    }
    acc.x += accB.x; acc.y += accB.y; acc.z += accB.z; acc.w += accB.w;

    float4 sacc = make_float4(acc.x * di, acc.y * di, acc.z * di, acc.w * di);
    int row = wv * 4 + sub;
    *(float4*)&g[row][fl * 4] = sacc;
    asm volatile("s_waitcnt lgkmcnt(0)" ::: "memory");

#pragma unroll
    for (int n = 0; n < 4; ++n) {
      const float4* gp = (const float4*)&g[wv * 4 + n][0];  // uniform broadcast
      float o = bl;
#pragma unroll
      for (int q = 0; q < 16; ++q) {
        float4 gv = gp[q];
        o = fmaf(gv.x, wreg[q * 4 + 0], o);
        o = fmaf(gv.y, wreg[q * 4 + 1], o);
        o = fmaf(gv.z, wreg[q * 4 + 2], o);
        o = fmaf(gv.w, wreg[q * 4 + 3], o);
      }
      float val = fmaxf(o, 0.f);
      if constexpr (SCALE_OUT) val *= dinv[i0 + n];
      if constexpr (BF16OUT) {
        size_t b = (size_t)(PADP + i0 + n) * 64 + lane;
        unsigned short hh = f2bf(val);
        xhi[b] = hh;
        xlo[b] = f2bf(val - bf2f(hh));
      } else {
        out[(size_t)(i0 + n) * 64 + lane] = val;
      }
    }
  }
}

// ---------------------------------------------------------------------------
// conv1 MFMA weights repack: idx = ((t*2+ks)*2+nf)*512 + lane*8 + i
//   o = nf*16 + (lane&15); c = ks*32 + (lane>>4)*8 + i; w = cw1[o][c][t]
// ---------------------------------------------------------------------------
__global__ __launch_bounds__(256) void k_wrepm(const float* __restrict__ w,
                                               unsigned short* __restrict__ whim,
                                               unsigned short* __restrict__ wlom) {
  int idx = blockIdx.x * 256 + threadIdx.x;
  if (idx >= 9 * 2 * 2 * 512) return;
  int i  = idx & 7;
  int l  = (idx >> 3) & 63;
  int nf = (idx >> 9) & 1;
  int ks = (idx >> 10) & 1;
  int t  = idx >> 11;
  int o = nf * 16 + (l & 15);
  int c = ks * 32 + (l >> 4) * 8 + i;
  float v = w[(o * 64 + c) * 9 + t];
  unsigned short h = f2bf(v);
  whim[idx] = h;
  wlom[idx] = f2bf(v - bf2f(h));
}

// conv2 MFMA weights repack (K=32, COUT=16): idx = t*512 + lane*8 + i
//   o = lane&15; c = (lane>>4)*8 + i; w = cw2[o][c][t]
__global__ __launch_bounds__(256) void k_wrepm2(const float* __restrict__ w,
                                                unsigned short* __restrict__ whim,
                                                unsigned short* __restrict__ wlom) {
  int idx = blockIdx.x * 256 + threadIdx.x;
  if (idx >= 9 * 512) return;
  int i = idx & 7;
  int l = (idx >> 3) & 63;
  int t = idx >> 9;
  int o = l & 15;
  int c = (l >> 4) * 8 + i;
  float v = w[(o * 32 + c) * 9 + t];
  unsigned short h = f2bf(v);
  whim[idx] = h;
  wlom[idx] = f2bf(v - bf2f(h));
}

// ---------------------------------------------------------------------------
// conv1 (64->32) implicit-GEMM via MFMA, LDS-staged (r14-proven structure).
// Epilogue: channels-last bf16 hi/lo into PADP2-padded arrays for conv2m.
// ---------------------------------------------------------------------------
__global__ __launch_bounds__(256) void k_conv1m(const unsigned short* __restrict__ xhi,
                                                const unsigned short* __restrict__ xlo,
                                                const unsigned short* __restrict__ whim,
                                                const unsigned short* __restrict__ wlom,
                                                const float* __restrict__ cb,
                                                unsigned short* __restrict__ y2hi,
                                                unsigned short* __restrict__ y2lo) {
  constexpr int PXS  = 80;           // bytes per px per half (64 data + 16 skew)
  constexpr int ROWB = 66 * PXS;     // 5280 B per staged row
  constexpr int HALF = 6 * ROWB;     // 31680 B per half (hi | lo)
  __shared__ __align__(16) unsigned char smem[2 * HALF];   // 63360 B

  int tid  = threadIdx.x;
  int lane = tid & 63, wv = tid >> 6;
  int sx = blockIdx.x & 7, gy = blockIdx.x >> 3;   // 8 x-strips, 128 y-groups
  int x0 = sx * 64, y0 = gy * 4;
  int lm = lane & 15, lc = lane >> 4;

  f32x4 acc[4][2];
#pragma unroll
  for (int mf = 0; mf < 4; ++mf)
#pragma unroll
    for (int nf = 0; nf < 2; ++nf) acc[mf][nf] = (f32x4){0.f, 0.f, 0.f, 0.f};

#pragma unroll 1
  for (int ks = 0; ks < 2; ++ks) {
    if (ks) __syncthreads();             // protect prev phase's reads
#pragma unroll 1
    for (int it = 0; it < 13; ++it) {
      int idx = it * 256 + tid;
      if (idx < 3168) {                  // 2 arr x 396 px x 4 chunks
        int arr = idx >= 1584;
        int rem = arr ? idx - 1584 : idx;
        int chunk = rem & 3;
        int pxr = rem >> 2;              // 0..395
        int r = pxr / 66, px = pxr - r * 66;
        int xx = x0 - 1 + px;
        uint4 v = make_uint4(0u, 0u, 0u, 0u);
        if (xx >= 0 && xx < GS) {
          size_t p = (size_t)(PADP + (y0 - 1 + r) * GS + xx);
          const unsigned short* src = arr ? xlo : xhi;
          v = *(const uint4*)((const unsigned char*)src + p * 128 + ks * 64 + chunk * 16);
        }
        *(uint4*)(smem + arr * HALF + r * ROWB + px * PXS + chunk * 16) = v;
      }
    }
    __syncthreads();
#pragma unroll 1
    for (int t = 0; t < 9; ++t) {
      int ky = t / 3, kx = t % 3;
      const unsigned short* wb = whim + (size_t)(((t * 2 + ks) * 2) * 64 + lane) * 8;
      const unsigned short* wl = wlom + (size_t)(((t * 2 + ks) * 2) * 64 + lane) * 8;
      s16x8 bh0 = *(const s16x8*)(wb);
      s16x8 bh1 = *(const s16x8*)(wb + 512);
      s16x8 bl0 = *(const s16x8*)(wl);
      s16x8 bl1 = *(const s16x8*)(wl + 512);
      int r = wv + ky;
#pragma unroll
      for (int mf = 0; mf < 4; ++mf) {
        int px = mf * 16 + lm + kx;
        const unsigned char* ap = smem + r * ROWB + px * PXS + lc * 16;
        s16x8 ah = *(const s16x8*)(ap);
        s16x8 al = *(const s16x8*)(ap + HALF);
        acc[mf][0] = __builtin_amdgcn_mfma_f32_16x16x32_bf16(ah, bh0, acc[mf][0], 0, 0, 0);
        acc[mf][0] = __builtin_amdgcn_mfma_f32_16x16x32_bf16(ah, bl0, acc[mf][0], 0, 0, 0);
        acc[mf][0] = __builtin_amdgcn_mfma_f32_16x16x32_bf16(al, bh0, acc[mf][0], 0, 0, 0);
        acc[mf][1] = __builtin_amdgcn_mfma_f32_16x16x32_bf16(ah, bh1, acc[mf][1], 0, 0, 0);
        acc[mf][1] = __builtin_amdgcn_mfma_f32_16x16x32_bf16(ah, bl1, acc[mf][1], 0, 0, 0);
        acc[mf][1] = __builtin_amdgcn_mfma_f32_16x16x32_bf16(al, bh1, acc[mf][1], 0, 0, 0);
      }
    }
  }
  __syncthreads();                       // all staged reads done; reuse LDS

  // epilogue: pixel-major via LDS -> channels-last bf16 hi/lo (+bias, relu)
  float* lds = (float*)smem;             // [4][64][33] floats = 33792 B
#pragma unroll
  for (int mf = 0; mf < 4; ++mf)
#pragma unroll
    for (int nf = 0; nf < 2; ++nf)
#pragma unroll
      for (int r = 0; r < 4; ++r)
        lds[((wv * 64 + mf * 16 + lc * 4 + r) * 33) + nf * 16 + lm] = acc[mf][nf][r];
  asm volatile("s_waitcnt lgkmcnt(0)" ::: "memory");

  size_t pp = (size_t)PADP2 + (size_t)(y0 + wv) * GS + x0 + lane;
  unsigned uh[16], ul[16];
#pragma unroll
  for (int o2 = 0; o2 < 16; ++o2) {
    float v0 = fmaxf(lds[(wv * 64 + lane) * 33 + 2 * o2]     + cb[2 * o2],     0.f);
    float v1 = fmaxf(lds[(wv * 64 + lane) * 33 + 2 * o2 + 1] + cb[2 * o2 + 1], 0.f);
    unsigned short h0 = f2bf(v0), h1 = f2bf(v1);
    unsigned short l0 = f2bf(v0 - bf2f(h0)), l1 = f2bf(v1 - bf2f(h1));
    uh[o2] = (unsigned)h0 | ((unsigned)h1 << 16);
    ul[o2] = (unsigned)l0 | ((unsigned)l1 << 16);
  }
  uint4* dh = (uint4*)(y2hi + pp * 32);
  uint4* dl = (uint4*)(y2lo + pp * 32);
#pragma unroll
  for (int q = 0; q < 4; ++q) {
    dh[q] = make_uint4(uh[q * 4], uh[q * 4 + 1], uh[q * 4 + 2], uh[q * 4 + 3]);
    dl[q] = make_uint4(ul[q * 4], ul[q * 4 + 1], ul[q * 4 + 2], ul[q * 4 + 3]);
  }
}

// ---------------------------------------------------------------------------
// conv2 (32->16) implicit-GEMM via MFMA: clone of conv1m, K=32 (one phase),
// COUT=16 (one nf). Output planar fp32 for the scalar conv3.
// ---------------------------------------------------------------------------
__global__ __launch_bounds__(256) void k_conv2m(const unsigned short* __restrict__ y2hi,
                                                const unsigned short* __restrict__ y2lo,
                                                const unsigned short* __restrict__ whim,
                                                const unsigned short* __restrict__ wlom,
                                                const float* __restrict__ cb,
                                                float* __restrict__ outp) {
  constexpr int PXS  = 80;           // 64 B data (32ch bf16) + 16 skew
  constexpr int ROWB = 66 * PXS;
  constexpr int HALF = 6 * ROWB;
  __shared__ __align__(16) unsigned char smem[2 * HALF];

  int tid  = threadIdx.x;
  int lane = tid & 63, wv = tid >> 6;
  int sx = blockIdx.x & 7, gy = blockIdx.x >> 3;
  int x0 = sx * 64, y0 = gy * 4;
  int lm = lane & 15, lc = lane >> 4;

  f32x4 acc[4];
#pragma unroll
  for (int mf = 0; mf < 4; ++mf) acc[mf] = (f32x4){0.f, 0.f, 0.f, 0.f};

  // stage: 6 rows x 66 px x 32 ch, hi+lo
#pragma unroll 1
  for (int it = 0; it < 13; ++it) {
    int idx = it * 256 + tid;
    if (idx < 3168) {
      int arr = idx >= 1584;
      int rem = arr ? idx - 1584 : idx;
      int chunk = rem & 3;
      int pxr = rem >> 2;
      int r = pxr / 66, px = pxr - r * 66;
      int xx = x0 - 1 + px;
      uint4 v = make_uint4(0u, 0u, 0u, 0u);
      if (xx >= 0 && xx < GS) {
        size_t p = (size_t)(PADP2 + (y0 - 1 + r) * GS + xx);
        const unsigned short* src = arr ? y2lo : y2hi;
        v = *(const uint4*)((const unsigned char*)src + p * 64 + chunk * 16);
      }
      *(uint4*)(smem + arr * HALF + r * ROWB + px * PXS + chunk * 16) = v;
    }
  }
  __syncthreads();
#pragma unroll 1
  for (int t = 0; t < 9; ++t) {
    int ky = t / 3, kx = t % 3;
    s16x8 bh = *(const s16x8*)(whim + ((size_t)t * 64 + lane) * 8);
    s16x8 bl = *(const s16x8*)(wlom + ((size_t)t * 64 + lane) * 8);
    int r = wv + ky;
#pragma unroll
    for (int mf = 0; mf < 4; ++mf) {
      int px = mf * 16 + lm + kx;
      const unsigned char* ap = smem + r * ROWB + px * PXS + lc * 16;
      s16x8 ah = *(const s16x8*)(ap);
      s16x8 al = *(const s16x8*)(ap + HALF);
      acc[mf] = __builtin_amdgcn_mfma_f32_16x16x32_bf16(ah, bh, acc[mf], 0, 0, 0);
      acc[mf] = __builtin_amdgcn_mfma_f32_16x16x32_bf16(ah, bl, acc[mf], 0, 0, 0);
      acc[mf] = __builtin_amdgcn_mfma_f32_16x16x32_bf16(al, bh, acc[mf], 0, 0, 0);
    }
  }
  __syncthreads();

  // epilogue: pixel-major via LDS -> planar fp32 + bias + relu
  float* lds = (float*)smem;             // [4][64][17] floats = 17408 B
#pragma unroll
  for (int mf = 0; mf < 4; ++mf)
#pragma unroll
    for (int r = 0; r < 4; ++r)
      lds[((wv * 64 + mf * 16 + lc * 4 + r) * 17) + lm] = acc[mf][r];
  asm volatile("s_waitcnt lgkmcnt(0)" ::: "memory");

  size_t ob = (size_t)(y0 + wv) * GS + x0 + lane;
#pragma unroll
  for (int o = 0; o < 16; ++o) {
    float v = lds[((wv * 64 + lane) * 17) + o] + cb[o];
    outp[(size_t)o * P + ob] = fmaxf(v, 0.f);
  }
}

// Repack conv weights OIHW -> group-major [g][c][tap][o_in_group]
template <int CIN, int COUT, int COUTB>
__global__ __launch_bounds__(256) void k_wrep(const float* __restrict__ w,
                                              float* __restrict__ wr) {
  int i = blockIdx.x * 256 + threadIdx.x;
  if (i >= CIN * 9 * COUT) return;
  int ol = i % COUTB;
  int t  = (i / COUTB) % 9;
  int c  = (i / (COUTB * 9)) % CIN;
  int g  = i / (COUTB * 9 * CIN);
  wr[i] = w[(((g * COUTB + ol) * CIN) + c) * 9 + t];
}

// ---------------------------------------------------------------------------
// Planar scalar 3x3 conv (layers 3-4), r10-proven config.
// ---------------------------------------------------------------------------
template <int CIN, int COUTB, bool RELU>
__global__ __launch_bounds__(256) void k_conv(const float* __restrict__ in,
                                              const float* __restrict__ wrep,
                                              const float* __restrict__ cb,
                                              float* __restrict__ out) {
  int tx = threadIdx.x;
  int ty = threadIdx.y;
  int g  = blockIdx.z;
  int x0 = (blockIdx.x * 64 + tx) * 2;
  int y  = blockIdx.y * 4 + ty;

  float acc0[COUTB], acc1[COUTB];
#pragma unroll
  for (int o = 0; o < COUTB; ++o) { acc0[o] = 0.f; acc1[o] = 0.f; }

  bool xlo = x0 > 0;
  bool xhi = x0 < GS - 2;
  int rok[3], yoff[3];
#pragma unroll
  for (int r = 0; r < 3; ++r) {
    int yy = y + r - 1;
    rok[r] = (yy >= 0) && (yy < GS);
    int yc = yy < 0 ? 0 : (yy > GS - 1 ? GS - 1 : yy);
    yoff[r] = yc * GS;
  }
  const float* wg = wrep + (size_t)g * CIN * 9 * COUTB;

  WFull<COUTB> w;
#pragma unroll 1
  for (int c = 0; c < CIN; ++c) {
    float iv[3][4];
#pragma unroll
    for (int r = 0; r < 3; ++r) {
      const float* ip = in + (size_t)c * P + yoff[r] + x0;
      if (rok[r]) {
        float2 m = *(const float2*)ip;
        iv[r][1] = m.x; iv[r][2] = m.y;
        iv[r][0] = xlo ? ip[-1] : 0.f;
        iv[r][3] = xhi ? ip[2]  : 0.f;
      } else {
        iv[r][0] = iv[r][1] = iv[r][2] = iv[r][3] = 0.f;
      }
    }
    w.load(wg + (size_t)c * 9 * COUTB);
#pragma unroll
    for (int t9 = 0; t9 < 9; ++t9) {
      int ky = t9 / 3, kx = t9 % 3;
      float a = iv[ky][kx], b2 = iv[ky][kx + 1];
#pragma unroll
      for (int o = 0; o < COUTB; ++o) {
        float wv = w.get(t9 * COUTB + o);
        acc0[o] = fmaf(a, wv, acc0[o]);
        acc1[o] = fmaf(b2, wv, acc1[o]);
      }
    }
  }

  size_t obase = (size_t)(g * COUTB) * P + (size_t)y * GS + x0;
#pragma unroll
  for (int o = 0; o < COUTB; ++o) {
    float bv = cb[g * COUTB + o];
    float v0 = acc0[o] + bv;
    float v1 = acc1[o] + bv;
    if (RELU) { v0 = fmaxf(v0, 0.f); v1 = fmaxf(v1, 0.f); }
    *(float2*)&out[obase + (size_t)o * P] = make_float2(v0, v1);
  }
}

// ---------------------------------------------------------------------------
extern "C" void kernel_launch(void* const* d_in, const int* in_sizes, int n_in,
                              void* d_out, int out_size, void* d_ws, size_t ws_size,
                              hipStream_t stream) {
  const float* x   = (const float*)d_in[0];
  const int*   esr = (const int*)d_in[1];
  const int*   eds = (const int*)d_in[2];
  const float* W1  = (const float*)d_in[4];
  const float* b1  = (const float*)d_in[5];
  const float* W2  = (const float*)d_in[6];
  const float* b2  = (const float*)d_in[7];
  const float* W3  = (const float*)d_in[8];
  const float* b3  = (const float*)d_in[9];
  const float* cw1 = (const float*)d_in[10];
  const float* cb1 = (const float*)d_in[11];
  const float* cw2 = (const float*)d_in[12];
  const float* cb2 = (const float*)d_in[13];
  const float* cw3 = (const float*)d_in[14];
  const float* cb3 = (const float*)d_in[15];
  const float* cw4 = (const float*)d_in[16];
  const float* cb4 = (const float*)d_in[17];
  float* out = (float*)d_out;

  char* ws = (char*)d_ws;
  const size_t MB = 1 << 20;
  const size_t KB = 1 << 10;
  const size_t XBYTES = (size_t)(P + 2 * PADP) * 64 * 2;   // 33,816,576
  // Region A [0,65MB): pairs -> xs -> hA(h1') -> {Xhi,Xlo} -> conv2out(16MB)
  unsigned*        pairs = (unsigned*)(ws);
  float*           xs    = (float*)(ws);
  float*           hA    = (float*)(ws);                    // h1' (64MB)
  unsigned short*  xhi   = (unsigned short*)(ws);           // 32.25MB
  unsigned short*  xlo   = (unsigned short*)(ws + XBYTES);  // 32.25MB
  float*           cA    = (float*)(ws);                    // conv2m out (16MB)
  // Region B [65MB,130MB): xagg -> hB(h2') -> {y2hi,y2lo} -> conv3out(8MB)
  float*           xagg  = (float*)(ws + 65 * MB);
  float*           hB    = (float*)(ws + 65 * MB);          // h2' (64MB+row)
  unsigned short*  y2hi  = (unsigned short*)(ws + 65 * MB); // 16.9MB
  unsigned short*  y2lo  = (unsigned short*)(ws + 83 * MB); // 16.9MB
  float*           cB8   = (float*)(ws + 101 * MB);         // conv3 out (8MB)
  int*             ssrc  = (int*)(ws + 130 * MB);
  float*           dinv  = (float*)(ws + 142 * MB + 8 * KB);
  int*             dgr   = (int*)(ws + 143 * MB + 16 * KB);
  int*             offs  = (int*)(ws + 144 * MB + 24 * KB);
  int*             gb    = (int*)(ws + 145 * MB + 32 * KB);
  int*             bbase = (int*)(ws + 145 * MB + 36 * KB);
  int*             bcur  = (int*)(ws + 145 * MB + 40 * KB);
  unsigned short*  whim  = (unsigned short*)(ws + 145 * MB + 48 * KB);   // 36KB
  unsigned short*  wlom  = (unsigned short*)(ws + 145 * MB + 88 * KB);   // 36KB
  float*           wr3   = (float*)(ws + 145 * MB + 128 * KB);           // 4.5KB
  float*           wr4   = wr3 + 16 * 9 * 8;                             // 1.7KB
  unsigned short*  whim2 = (unsigned short*)(ws + 145 * MB + 160 * KB);  // 9KB
  unsigned short*  wlom2 = (unsigned short*)(ws + 145 * MB + 176 * KB);  // 9KB

  // ---- weight repacks ----
  k_wrepm<<<72, 256, 0, stream>>>(cw1, whim, wlom);
  k_wrepm2<<<18, 256, 0, stream>>>(cw2, whim2, wlom2);
  k_wrep<16,  8, 8><<<(16 * 9 *  8 + 255) / 256, 256, 0, stream>>>(cw3, wr3);
  k_wrep< 8,  6, 6><<<( 8 * 9 *  6 + 255) / 256, 256, 0, stream>>>(cw4, wr4);

  // ---- CSR build ----
  hipMemsetAsync(gb, 0, 256 * sizeof(int), stream);
  k_bhist<<<512, 256, 0, stream>>>((const int4*)eds, gb);
  k_bscan<<<1, 256, 0, stream>>>(gb, bbase, bcur);
  k_bin<<<512, 256, 0, stream>>>((const int4*)esr, (const int4*)eds, bcur, pairs);
  k_bsort<<<256, 256, 0, stream>>>(pairs, bbase, ssrc, offs, dgr, dinv);

  // ---- GCN ----
  k_zrows<<<1, 256, 0, stream>>>(hA, hB, xs);
  k_xscale<<<NN / 256, 256, 0, stream>>>((const float4*)x, dinv, (float4*)xs);
  k_agg4<<<1024, 256, 0, stream>>>((const float4*)xs, dinv, offs, dgr,
                                   (const int4*)ssrc, (float4*)xagg);
  k_matmul4<<<2048, 256, 0, stream>>>(xagg, W1, b1, dinv, hA);
  k_aggW<true, false><<<2048, 256, 0, stream>>>(hA, dinv, offs, dgr,
                                                (const int4*)ssrc, W2, b2, hB,
                                                nullptr, nullptr);
  // zero the X pads (h1' region dead), then layer 3 -> bf16 hi/lo
  const size_t PADB = (size_t)PADP * 64 * 2;               // 128KB
  hipMemsetAsync((char*)xhi, 0, PADB, stream);
  hipMemsetAsync((char*)xhi + (size_t)(PADP + P) * 128, 0, PADB, stream);
  hipMemsetAsync((char*)xlo, 0, PADB, stream);
  hipMemsetAsync((char*)xlo + (size_t)(PADP + P) * 128, 0, PADB, stream);
  k_aggW<false, true><<<2048, 256, 0, stream>>>(hB, dinv, offs, dgr,
                                                (const int4*)ssrc, W3, b3, hB,
                                                xhi, xlo);

  // ---- CNN ----
  // y2 pads (hB dead after layer 3)
  const size_t PADB2 = (size_t)PADP2 * 32 * 2;             // 64KB
  hipMemsetAsync((char*)y2hi, 0, PADB2, stream);
  hipMemsetAsync((char*)y2hi + (size_t)(PADP2 + P) * 64, 0, PADB2, stream);
  hipMemsetAsync((char*)y2lo, 0, PADB2, stream);
  hipMemsetAsync((char*)y2lo + (size_t)(PADP2 + P) * 64, 0, PADB2, stream);
  k_conv1m<<<1024, 256, 0, stream>>>(xhi, xlo, whim, wlom, cb1, y2hi, y2lo);
  k_conv2m<<<1024, 256, 0, stream>>>(y2hi, y2lo, whim2, wlom2, cb2, cA);
  k_conv<16, 8, true ><<<dim3(4, 128, 1), dim3(64, 4), 0, stream>>>(cA, wr3, cb3, cB8);
  k_conv< 8, 6, false><<<dim3(4, 128, 1), dim3(64, 4), 0, stream>>>(cB8, wr4, cb4, out);
}